// Round 1
// baseline (940.632 us; speedup 1.0000x reference)
//
#include <hip/hip_runtime.h>
#include <hip/hip_bf16.h>
#include <cstdint>
#include <cstddef>

#define NN 4096
#define NE 65536
#define HD 256

typedef __attribute__((ext_vector_type(4))) float f32x4;
typedef __attribute__((ext_vector_type(8))) __bf16 bf16x8;

static __device__ __forceinline__ float silu_f(float v) {
  return v / (1.f + __expf(-v));
}

// ---------------- weight transpose/convert: f32 [K,N] -> bf16 [N,K] ----------
struct TJob { const float* src; __bf16* dst; int K; int N; };
struct TJobs { TJob j[39]; };

__global__ __launch_bounds__(256) void k_transpose(TJobs jobs) {
  TJob jb = jobs.j[blockIdx.z];
  int k0 = blockIdx.x << 5, n0 = blockIdx.y << 5;
  if (k0 >= jb.K || n0 >= jb.N) return;
  __shared__ float t[32][33];
  int tx = threadIdx.x & 31, ty = threadIdx.x >> 5;
#pragma unroll
  for (int r = ty; r < 32; r += 8)
    t[r][tx] = jb.src[(size_t)(k0 + r) * jb.N + n0 + tx];
  __syncthreads();
#pragma unroll
  for (int r = ty; r < 32; r += 8)
    jb.dst[(size_t)(n0 + r) * jb.K + k0 + tx] = (__bf16)t[tx][r];
}

// ---------------- CSR build ----------------
__global__ __launch_bounds__(256) void k_hist(const int* __restrict__ ei, int* __restrict__ cnt) {
  int e = blockIdx.x * 256 + threadIdx.x;
  atomicAdd(&cnt[ei[e]], 1);
}

__global__ __launch_bounds__(1024) void k_scan(const int* __restrict__ cnt, int* __restrict__ offs,
                                               int* __restrict__ cursor) {
  __shared__ int tmp[1024];
  int tid = threadIdx.x;
  int v[4]; int s = 0;
#pragma unroll
  for (int i = 0; i < 4; i++) { v[i] = cnt[tid * 4 + i]; s += v[i]; }
  tmp[tid] = s;
  __syncthreads();
  for (int o = 1; o < 1024; o <<= 1) {
    int t = (tid >= o) ? tmp[tid - o] : 0;
    __syncthreads();
    tmp[tid] += t;
    __syncthreads();
  }
  int base = (tid > 0) ? tmp[tid - 1] : 0;
#pragma unroll
  for (int i = 0; i < 4; i++) {
    offs[tid * 4 + i] = base; cursor[tid * 4 + i] = base; base += v[i];
  }
  if (tid == 1023) offs[4096] = base;
}

__global__ __launch_bounds__(256) void k_scatter(const int* __restrict__ ei, int* __restrict__ cursor,
                                                 int* __restrict__ elist) {
  int e = blockIdx.x * 256 + threadIdx.x;
  int pos = atomicAdd(&cursor[ei[e]], 1);
  elist[pos] = e;
}

// ---------------- misc small kernels ----------------
__global__ __launch_bounds__(256) void k_copyx(const float* __restrict__ x, float* __restrict__ xc) {
  int i = blockIdx.x * 256 + threadIdx.x;
  if (i < NN * 3) xc[i] = x[i];
}

__global__ __launch_bounds__(256) void k_dist0(const int* __restrict__ ei, const float* __restrict__ x,
                                               float* __restrict__ dist0) {
  int e = blockIdx.x * 256 + threadIdx.x;
  int r = ei[e], c = ei[NE + e];
  float dx = x[r * 3 + 0] - x[c * 3 + 0];
  float dy = x[r * 3 + 1] - x[c * 3 + 1];
  float dz = x[r * 3 + 2] - x[c * 3 + 2];
  dist0[e] = dx * dx + dy * dy + dz * dz;
}

__global__ __launch_bounds__(256) void k_edgegeo(const int* __restrict__ ei, const float* __restrict__ x,
                                                 float* __restrict__ radial, float* __restrict__ cd) {
  int e = blockIdx.x * 256 + threadIdx.x;
  int r = ei[e], c = ei[NE + e];
  float dx = x[r * 3 + 0] - x[c * 3 + 0];
  float dy = x[r * 3 + 1] - x[c * 3 + 1];
  float dz = x[r * 3 + 2] - x[c * 3 + 2];
  float rad = dx * dx + dy * dy + dz * dz;
  radial[e] = rad;
  float inv = 1.f / (sqrtf(rad + 1e-8f) + 1.f);
  cd[e * 3 + 0] = dx * inv; cd[e * 3 + 1] = dy * inv; cd[e * 3 + 2] = dz * inv;
}

__global__ __launch_bounds__(256) void k_embed(const float* __restrict__ h0, const float* __restrict__ W,
                                               const float* __restrict__ b, float* __restrict__ hf,
                                               __bf16* __restrict__ h16) {
  int n = blockIdx.x, c = threadIdx.x;
  float s = b[c];
#pragma unroll
  for (int i = 0; i < 16; i++) s += h0[n * 16 + i] * W[i * 256 + c];
  hf[(size_t)n * HD + c] = s;
  h16[(size_t)n * HD + c] = (__bf16)s;
}

// fused edge-MLP layer1: m1[e] = silu(P[row] + Q[col] + rad*w512 + d0*w513 + b1)
__global__ __launch_bounds__(256) void k_edge1(const int* __restrict__ ei, const float* __restrict__ PQ,
                                               const float* __restrict__ radial, const float* __restrict__ dist0,
                                               const float* __restrict__ w1, const float* __restrict__ b1,
                                               __bf16* __restrict__ m1) {
  int e = (blockIdx.x << 2) + (threadIdx.x >> 6);
  int c = (threadIdx.x & 63) << 2;
  int r = ei[e], cl = ei[NE + e];
  float rad = radial[e], d0 = dist0[e];
  float4 pv = *(const float4*)(PQ + (size_t)r * 512 + c);
  float4 qv = *(const float4*)(PQ + (size_t)cl * 512 + 256 + c);
  float4 wr = *(const float4*)(w1 + 512 * 256 + c);
  float4 wd = *(const float4*)(w1 + 513 * 256 + c);
  float4 bb = *(const float4*)(b1 + c);
  float vv[4] = { pv.x + qv.x + rad * wr.x + d0 * wd.x + bb.x,
                  pv.y + qv.y + rad * wr.y + d0 * wd.y + bb.y,
                  pv.z + qv.z + rad * wr.z + d0 * wd.z + bb.z,
                  pv.w + qv.w + rad * wr.w + d0 * wd.w + bb.w };
  union { __bf16 h[4]; uint2 u; } o;
#pragma unroll
  for (int j = 0; j < 4; j++) o.h[j] = (__bf16)silu_f(vv[j]);
  *(uint2*)(m1 + (size_t)e * HD + c) = o.u;
}

// seg-sum over CSR + build ncat = [h16 | agg/100]
__global__ __launch_bounds__(256) void k_segsum(const __bf16* __restrict__ m2, const int* __restrict__ offs,
                                                const int* __restrict__ elist, const __bf16* __restrict__ h16,
                                                __bf16* __restrict__ ncat) {
  int n = blockIdx.x, c = threadIdx.x;
  float s = 0.f;
  int i1 = offs[n + 1];
  for (int i = offs[n]; i < i1; i++) {
    int e = elist[i];
    s += (float)m2[(size_t)e * HD + c];
  }
  ncat[(size_t)n * 512 + c] = h16[(size_t)n * HD + c];
  ncat[(size_t)n * 512 + 256 + c] = (__bf16)(s * 0.01f);
}

// per-edge: s = dot(t2[e], w3); trans[e] = cd[e]*s
__global__ __launch_bounds__(256) void k_coord3(const __bf16* __restrict__ t2, const float* __restrict__ w3,
                                                const float* __restrict__ cd, float* __restrict__ trans) {
  int e = (blockIdx.x << 2) + (threadIdx.x >> 6);
  int lane = threadIdx.x & 63;
  int c = lane << 2;
  float s = 0.f;
#pragma unroll
  for (int j = 0; j < 4; j++) s += (float)t2[(size_t)e * HD + c + j] * w3[c + j];
#pragma unroll
  for (int o = 32; o > 0; o >>= 1) s += __shfl_down(s, o, 64);
  if (lane == 0) {
    trans[e * 3 + 0] = cd[e * 3 + 0] * s;
    trans[e * 3 + 1] = cd[e * 3 + 1] * s;
    trans[e * 3 + 2] = cd[e * 3 + 2] * s;
  }
}

__global__ __launch_bounds__(256) void k_xupd(const float* __restrict__ trans, const int* __restrict__ offs,
                                              const int* __restrict__ elist, float* __restrict__ xc) {
  int n = blockIdx.x * 256 + threadIdx.x;
  if (n >= NN) return;
  float a0 = 0.f, a1 = 0.f, a2 = 0.f;
  int i1 = offs[n + 1];
  for (int i = offs[n]; i < i1; i++) {
    int e = elist[i];
    a0 += trans[e * 3 + 0]; a1 += trans[e * 3 + 1]; a2 += trans[e * 3 + 2];
  }
  xc[n * 3 + 0] += a0 * 0.01f;
  xc[n * 3 + 1] += a1 * 0.01f;
  xc[n * 3 + 2] += a2 * 0.01f;
}

__global__ __launch_bounds__(256) void k_outh(const float* __restrict__ hf, const float* __restrict__ W,
                                              const float* __restrict__ b, float* __restrict__ out) {
  int t = blockIdx.x * 256 + threadIdx.x;
  int n = t >> 4, j = t & 15;
  float s = b[j];
  for (int c = 0; c < 256; c++) s += hf[(size_t)n * HD + c] * W[c * 16 + j];
  out[n * 16 + j] = s;
}

__global__ __launch_bounds__(256) void k_outx(const float* __restrict__ xc, float* __restrict__ out) {
  int i = blockIdx.x * 256 + threadIdx.x;
  if (i < NN * 3) out[i] = xc[i];
}

// ---------------- MFMA GEMM ----------------
// C[M,N] = epi(A[M,K] @ B^T  + bias), A row-major bf16 (ld=K), B given as [N,K] bf16.
// EPI: 1 = silu -> outb bf16 ; 2 = outf(f32) += v, outb = bf16(outf) ; 3 = outf f32 plain (no bias)
template <int BM, int BN, int EPI>
__global__ __launch_bounds__(256) void k_gemm(const __bf16* __restrict__ A, const __bf16* __restrict__ Bt,
                                              const float* __restrict__ bias, __bf16* __restrict__ outb,
                                              float* __restrict__ outf, int M, int N, int K) {
  constexpr int BK = 64;
  constexpr int GR = BK / 8;          // 16B granules per row
  constexpr int TM = BM / 2, TN = BN / 2;
  constexpr int FM = TM / 16, FN = TN / 16;
  __shared__ alignas(16) __bf16 As[BM * BK];
  __shared__ alignas(16) __bf16 Bs[BN * BK];
  const int tid = threadIdx.x;
  const int lane = tid & 63;
  const int wave = tid >> 6;
  const int wm = wave >> 1, wn = wave & 1;
  const size_t m0 = (size_t)blockIdx.x * BM;
  const size_t n0 = (size_t)blockIdx.y * BN;

  f32x4 acc[FM][FN] = {};

  for (int kt = 0; kt < K; kt += BK) {
    for (int i = tid; i < BM * GR; i += 256) {
      int r = i / GR, g = i % GR;
      uint4 v = *reinterpret_cast<const uint4*>(A + (m0 + r) * K + kt + g * 8);
      int gs = g ^ (r & 7);
      *reinterpret_cast<uint4*>(&As[r * BK + gs * 8]) = v;
    }
    for (int i = tid; i < BN * GR; i += 256) {
      int r = i / GR, g = i % GR;
      uint4 v = *reinterpret_cast<const uint4*>(Bt + (n0 + r) * K + kt + g * 8);
      int gs = g ^ (r & 7);
      *reinterpret_cast<uint4*>(&Bs[r * BK + gs * 8]) = v;
    }
    __syncthreads();
#pragma unroll
    for (int ks = 0; ks < BK; ks += 32) {
      const int kg = (ks >> 3) + (lane >> 4);
      bf16x8 af[FM], bfr[FN];
#pragma unroll
      for (int fm = 0; fm < FM; fm++) {
        int r = wm * TM + fm * 16 + (lane & 15);
        int gs = kg ^ (r & 7);
        af[fm] = *reinterpret_cast<const bf16x8*>(&As[r * BK + gs * 8]);
      }
#pragma unroll
      for (int fn = 0; fn < FN; fn++) {
        int r = wn * TN + fn * 16 + (lane & 15);
        int gs = kg ^ (r & 7);
        bfr[fn] = *reinterpret_cast<const bf16x8*>(&Bs[r * BK + gs * 8]);
      }
#pragma unroll
      for (int fm = 0; fm < FM; fm++)
#pragma unroll
        for (int fn = 0; fn < FN; fn++)
          acc[fm][fn] = __builtin_amdgcn_mfma_f32_16x16x32_bf16(af[fm], bfr[fn], acc[fm][fn], 0, 0, 0);
    }
    __syncthreads();
  }

#pragma unroll
  for (int fm = 0; fm < FM; fm++) {
#pragma unroll
    for (int fn = 0; fn < FN; fn++) {
      const size_t col = n0 + wn * TN + fn * 16 + (lane & 15);
      float bv = (EPI == 3) ? 0.f : bias[col];
#pragma unroll
      for (int j = 0; j < 4; j++) {
        size_t row = m0 + wm * TM + fm * 16 + ((lane >> 4) << 2) + j;
        size_t idx = row * (size_t)N + col;
        float v = acc[fm][fn][j] + bv;
        if (EPI == 1) {
          outb[idx] = (__bf16)silu_f(v);
        } else if (EPI == 2) {
          float nh = outf[idx] + v;
          outf[idx] = nh;
          outb[idx] = (__bf16)nh;
        } else {
          outf[idx] = v;
        }
      }
    }
  }
}

// ---------------- host ----------------
extern "C" void kernel_launch(void* const* d_in, const int* in_sizes, int n_in,
                              void* d_out, int out_size, void* d_ws, size_t ws_size,
                              hipStream_t stream) {
  const float* h_in    = (const float*)d_in[0];
  const float* x_in    = (const float*)d_in[1];
  const int*   ei      = (const int*)d_in[2];
  const float* emb_w   = (const float*)d_in[3];
  const float* emb_b   = (const float*)d_in[4];
  const float* out_w   = (const float*)d_in[5];
  const float* out_b   = (const float*)d_in[6];
  const float* edge_w1 = (const float*)d_in[7];
  const float* edge_b1 = (const float*)d_in[8];
  const float* edge_w2 = (const float*)d_in[9];
  const float* edge_b2 = (const float*)d_in[10];
  const float* node_w1 = (const float*)d_in[11];
  const float* node_b1 = (const float*)d_in[12];
  const float* node_w2 = (const float*)d_in[13];
  const float* node_b2 = (const float*)d_in[14];
  const float* coord_w1 = (const float*)d_in[15];
  const float* coord_b1 = (const float*)d_in[16];
  const float* coord_w2 = (const float*)d_in[17];
  const float* coord_b2 = (const float*)d_in[18];
  const float* coord_w3 = (const float*)d_in[19];

  char* p = (char*)d_ws;
  auto alloc = [&](size_t bytes) -> void* {
    void* r = (void*)p;
    p += (bytes + 255) & ~(size_t)255;
    return r;
  };
  __bf16* e1T  = (__bf16*)alloc((size_t)6 * 512 * 256 * 2);  // per gi: [512,256] = [W1a^T; W1b^T]
  __bf16* e2T  = (__bf16*)alloc((size_t)6 * 256 * 256 * 2);
  __bf16* n1T  = (__bf16*)alloc((size_t)6 * 256 * 512 * 2);  // [256,512]
  __bf16* n2T  = (__bf16*)alloc((size_t)6 * 256 * 256 * 2);
  __bf16* c1T  = (__bf16*)alloc((size_t)3 * 512 * 256 * 2);
  __bf16* c2T  = (__bf16*)alloc((size_t)3 * 256 * 256 * 2);
  __bf16* h16  = (__bf16*)alloc((size_t)NN * HD * 2);
  __bf16* m1   = (__bf16*)alloc((size_t)NE * HD * 2);
  __bf16* m2   = (__bf16*)alloc((size_t)NE * HD * 2);
  __bf16* ncat = (__bf16*)alloc((size_t)NN * 512 * 2);
  __bf16* u    = (__bf16*)alloc((size_t)NN * HD * 2);
  float* hf    = (float*)alloc((size_t)NN * HD * 4);
  float* PQ    = (float*)alloc((size_t)NN * 512 * 4);
  float* xc    = (float*)alloc((size_t)NN * 3 * 4);
  float* dist0 = (float*)alloc((size_t)NE * 4);
  float* radial = (float*)alloc((size_t)NE * 4);
  float* cd    = (float*)alloc((size_t)NE * 3 * 4);
  float* trans = (float*)alloc((size_t)NE * 3 * 4);
  int* cnt     = (int*)alloc((size_t)NN * 4);
  int* offs    = (int*)alloc((size_t)(NN + 1) * 4);
  int* cursor  = (int*)alloc((size_t)NN * 4);
  int* elist   = (int*)alloc((size_t)NE * 4);

  TJobs jobs;
  int nj = 0;
  for (int gi = 0; gi < 6; gi++) {
    jobs.j[nj++] = { edge_w1 + (size_t)gi * 514 * 256,             e1T + (size_t)gi * 512 * 256,             256, 256 };
    jobs.j[nj++] = { edge_w1 + (size_t)gi * 514 * 256 + 256 * 256, e1T + (size_t)gi * 512 * 256 + 256 * 256, 256, 256 };
    jobs.j[nj++] = { edge_w2 + (size_t)gi * 256 * 256,             e2T + (size_t)gi * 256 * 256,             256, 256 };
    jobs.j[nj++] = { node_w1 + (size_t)gi * 512 * 256,             n1T + (size_t)gi * 256 * 512,             512, 256 };
    jobs.j[nj++] = { node_w2 + (size_t)gi * 256 * 256,             n2T + (size_t)gi * 256 * 256,             256, 256 };
  }
  for (int b = 0; b < 3; b++) {
    jobs.j[nj++] = { coord_w1 + (size_t)b * 514 * 256,             c1T + (size_t)b * 512 * 256,              256, 256 };
    jobs.j[nj++] = { coord_w1 + (size_t)b * 514 * 256 + 256 * 256, c1T + (size_t)b * 512 * 256 + 256 * 256,  256, 256 };
    jobs.j[nj++] = { coord_w2 + (size_t)b * 256 * 256,             c2T + (size_t)b * 256 * 256,              256, 256 };
  }

  hipMemsetAsync(cnt, 0, (size_t)NN * 4, stream);
  k_transpose<<<dim3(16, 8, 39), 256, 0, stream>>>(jobs);
  k_hist<<<NE / 256, 256, 0, stream>>>(ei, cnt);
  k_scan<<<1, 1024, 0, stream>>>(cnt, offs, cursor);
  k_scatter<<<NE / 256, 256, 0, stream>>>(ei, cursor, elist);
  k_copyx<<<(NN * 3 + 255) / 256, 256, 0, stream>>>(x_in, xc);
  k_dist0<<<NE / 256, 256, 0, stream>>>(ei, x_in, dist0);
  k_embed<<<NN, 256, 0, stream>>>(h_in, emb_w, emb_b, hf, h16);

  int gi = 0;
  for (int b = 0; b < 3; b++) {
    k_edgegeo<<<NE / 256, 256, 0, stream>>>(ei, xc, radial, cd);
    for (int s = 0; s < 2; s++, gi++) {
      // PQ = h @ [W1a|W1b]   (M=4096, N=512, K=256) f32 out
      k_gemm<64, 64, 3><<<dim3(64, 8), 256, 0, stream>>>(
          h16, e1T + (size_t)gi * 512 * 256, nullptr, nullptr, PQ, NN, 512, 256);
      k_edge1<<<NE / 4, 256, 0, stream>>>(ei, PQ, radial, dist0,
          edge_w1 + (size_t)gi * 514 * 256, edge_b1 + gi * 256, m1);
      // m2 = silu(m1 @ W2 + b2)   (M=65536)
      k_gemm<128, 128, 1><<<dim3(512, 2), 256, 0, stream>>>(
          m1, e2T + (size_t)gi * 256 * 256, edge_b2 + gi * 256, m2, nullptr, NE, 256, 256);
      k_segsum<<<NN, 256, 0, stream>>>(m2, offs, elist, h16, ncat);
      // u = silu(ncat @ Wn1 + bn1)  (K=512)
      k_gemm<64, 64, 1><<<dim3(64, 4), 256, 0, stream>>>(
          ncat, n1T + (size_t)gi * 256 * 512, node_b1 + gi * 256, u, nullptr, NN, 256, 512);
      // h += u @ Wn2 + bn2 (residual, updates hf and h16)
      k_gemm<64, 64, 2><<<dim3(64, 4), 256, 0, stream>>>(
          u, n2T + (size_t)gi * 256 * 256, node_b2 + gi * 256, h16, hf, NN, 256, 256);
    }
    // coord MLP
    k_gemm<64, 64, 3><<<dim3(64, 8), 256, 0, stream>>>(
        h16, c1T + (size_t)b * 512 * 256, nullptr, nullptr, PQ, NN, 512, 256);
    k_edge1<<<NE / 4, 256, 0, stream>>>(ei, PQ, radial, dist0,
        coord_w1 + (size_t)b * 514 * 256, coord_b1 + b * 256, m1);
    k_gemm<128, 128, 1><<<dim3(512, 2), 256, 0, stream>>>(
        m1, c2T + (size_t)b * 256 * 256, coord_b2 + b * 256, m2, nullptr, NE, 256, 256);
    k_coord3<<<NE / 4, 256, 0, stream>>>(m2, coord_w3 + b * 256, cd, trans);
    k_xupd<<<NN / 256, 256, 0, stream>>>(trans, offs, elist, xc);
  }
  k_outh<<<NN * 16 / 256, 256, 0, stream>>>(hf, out_w, out_b, (float*)d_out);
  k_outx<<<(NN * 3 + 255) / 256, 256, 0, stream>>>(xc, (float*)d_out + (size_t)NN * 16);
}

// Round 2
// 571.325 us; speedup vs baseline: 1.6464x; 1.6464x over previous
//
#include <hip/hip_runtime.h>
#include <hip/hip_bf16.h>
#include <cstdint>
#include <cstddef>

#define NN 4096
#define NE 65536
#define HD 256

typedef __attribute__((ext_vector_type(4))) float f32x4;
typedef __attribute__((ext_vector_type(8))) __bf16 bf16x8;

static __device__ __forceinline__ float silu_f(float v) {
  return v / (1.f + __expf(-v));
}

// ---------------- weight transpose/convert: f32 [K,N] -> bf16 [N,K] ----------
struct TJob { const float* src; __bf16* dst; int K; int N; };
struct TJobs { TJob j[39]; };

__global__ __launch_bounds__(256) void k_transpose(TJobs jobs) {
  TJob jb = jobs.j[blockIdx.z];
  int k0 = blockIdx.x << 5, n0 = blockIdx.y << 5;
  if (k0 >= jb.K || n0 >= jb.N) return;
  __shared__ float t[32][33];
  int tx = threadIdx.x & 31, ty = threadIdx.x >> 5;
#pragma unroll
  for (int r = ty; r < 32; r += 8)
    t[r][tx] = jb.src[(size_t)(k0 + r) * jb.N + n0 + tx];
  __syncthreads();
#pragma unroll
  for (int r = ty; r < 32; r += 8)
    jb.dst[(size_t)(n0 + r) * jb.K + k0 + tx] = (__bf16)t[tx][r];
}

// ---------------- CSR build ----------------
__global__ __launch_bounds__(256) void k_hist(const int* __restrict__ ei, int* __restrict__ cnt) {
  int e = blockIdx.x * 256 + threadIdx.x;
  atomicAdd(&cnt[ei[e]], 1);
}

__global__ __launch_bounds__(1024) void k_scan(const int* __restrict__ cnt, int* __restrict__ offs,
                                               int* __restrict__ cursor) {
  __shared__ int tmp[1024];
  int tid = threadIdx.x;
  int v[4]; int s = 0;
#pragma unroll
  for (int i = 0; i < 4; i++) { v[i] = cnt[tid * 4 + i]; s += v[i]; }
  tmp[tid] = s;
  __syncthreads();
  for (int o = 1; o < 1024; o <<= 1) {
    int t = (tid >= o) ? tmp[tid - o] : 0;
    __syncthreads();
    tmp[tid] += t;
    __syncthreads();
  }
  int base = (tid > 0) ? tmp[tid - 1] : 0;
#pragma unroll
  for (int i = 0; i < 4; i++) {
    offs[tid * 4 + i] = base; cursor[tid * 4 + i] = base; base += v[i];
  }
  if (tid == 1023) offs[4096] = base;
}

__global__ __launch_bounds__(256) void k_scatter(const int* __restrict__ ei, int* __restrict__ cursor,
                                                 int* __restrict__ elist) {
  int e = blockIdx.x * 256 + threadIdx.x;
  int pos = atomicAdd(&cursor[ei[e]], 1);
  elist[pos] = e;
}

// CSR metadata + dist0 (from initial x), all in CSR position order
__global__ __launch_bounds__(256) void k_csrinit(const int* __restrict__ elist, const int* __restrict__ ei,
                                                 const float* __restrict__ x, int* __restrict__ rowp,
                                                 int* __restrict__ colp, float* __restrict__ d0p) {
  int i = blockIdx.x * 256 + threadIdx.x;
  int e = elist[i];
  int r = ei[e], c = ei[NE + e];
  rowp[i] = r; colp[i] = c;
  float dx = x[r * 3 + 0] - x[c * 3 + 0];
  float dy = x[r * 3 + 1] - x[c * 3 + 1];
  float dz = x[r * 3 + 2] - x[c * 3 + 2];
  d0p[i] = dx * dx + dy * dy + dz * dz;
}

// per-block geometry (radial + coord_diff) in CSR order, from current coords
__global__ __launch_bounds__(256) void k_geo(const int* __restrict__ rowp, const int* __restrict__ colp,
                                             const float* __restrict__ x, float* __restrict__ radp,
                                             float* __restrict__ cdp) {
  int i = blockIdx.x * 256 + threadIdx.x;
  int r = rowp[i], c = colp[i];
  float dx = x[r * 3 + 0] - x[c * 3 + 0];
  float dy = x[r * 3 + 1] - x[c * 3 + 1];
  float dz = x[r * 3 + 2] - x[c * 3 + 2];
  float rad = dx * dx + dy * dy + dz * dz;
  radp[i] = rad;
  float inv = 1.f / (sqrtf(rad + 1e-8f) + 1.f);
  cdp[i * 3 + 0] = dx * inv; cdp[i * 3 + 1] = dy * inv; cdp[i * 3 + 2] = dz * inv;
}

// ---------------- misc small kernels ----------------
__global__ __launch_bounds__(256) void k_copyx(const float* __restrict__ x, float* __restrict__ xc) {
  int i = blockIdx.x * 256 + threadIdx.x;
  if (i < NN * 3) xc[i] = x[i];
}

__global__ __launch_bounds__(256) void k_embed(const float* __restrict__ h0, const float* __restrict__ W,
                                               const float* __restrict__ b, float* __restrict__ hf,
                                               __bf16* __restrict__ h16) {
  int n = blockIdx.x, c = threadIdx.x;
  float s = b[c];
#pragma unroll
  for (int i = 0; i < 16; i++) s += h0[n * 16 + i] * W[i * 256 + c];
  hf[(size_t)n * HD + c] = s;
  h16[(size_t)n * HD + c] = (__bf16)s;
}

// seg-sum over CSR (m2p is CSR-ordered -> streaming reads) + build ncat = [h16 | agg/100]
__global__ __launch_bounds__(256) void k_segsum(const __bf16* __restrict__ m2p, const int* __restrict__ offs,
                                                const __bf16* __restrict__ h16, __bf16* __restrict__ ncat) {
  __shared__ float sd[8][256];
  int n = blockIdx.x, t = threadIdx.x;
  int g = t >> 5, l = t & 31;
  int c0 = l << 3;
  float a[8] = {};
  int ib = offs[n], ie = offs[n + 1];
  for (int i = ib + g; i < ie; i += 8) {
    bf16x8 v = *(const bf16x8*)(m2p + (size_t)i * 256 + c0);
#pragma unroll
    for (int j = 0; j < 8; j++) a[j] += (float)v[j];
  }
#pragma unroll
  for (int j = 0; j < 8; j++) sd[g][c0 + j] = a[j];
  __syncthreads();
  float s = 0.f;
#pragma unroll
  for (int j = 0; j < 8; j++) s += sd[j][t];
  ncat[(size_t)n * 512 + t] = h16[(size_t)n * HD + t];
  ncat[(size_t)n * 512 + 256 + t] = (__bf16)(s * 0.01f);
}

__global__ __launch_bounds__(256) void k_xupd(const float* __restrict__ transp, const int* __restrict__ offs,
                                              float* __restrict__ xc) {
  int n = blockIdx.x * 256 + threadIdx.x;
  if (n >= NN) return;
  float a0 = 0.f, a1 = 0.f, a2 = 0.f;
  int i1 = offs[n + 1];
  for (int i = offs[n]; i < i1; i++) {
    a0 += transp[i * 3 + 0]; a1 += transp[i * 3 + 1]; a2 += transp[i * 3 + 2];
  }
  xc[n * 3 + 0] += a0 * 0.01f;
  xc[n * 3 + 1] += a1 * 0.01f;
  xc[n * 3 + 2] += a2 * 0.01f;
}

__global__ __launch_bounds__(256) void k_outh(const float* __restrict__ hf, const float* __restrict__ W,
                                              const float* __restrict__ b, float* __restrict__ out) {
  int t = blockIdx.x * 256 + threadIdx.x;
  int n = t >> 4, j = t & 15;
  float s = b[j];
  for (int c = 0; c < 256; c++) s += hf[(size_t)n * HD + c] * W[c * 16 + j];
  out[n * 16 + j] = s;
}

__global__ __launch_bounds__(256) void k_outx(const float* __restrict__ xc, float* __restrict__ out) {
  int i = blockIdx.x * 256 + threadIdx.x;
  if (i < NN * 3) out[i] = xc[i];
}

// ---------------- fused edge-block kernel ----------------
// Computes, for 128 CSR-ordered edges x all 256 outputs:
//   m1[e][k] = silu(PQ[row][k] + PQ[col][256+k] + rad*w1r[k] + d0*w1d[k] + b1[k])  (on the fly, into LDS)
//   out      = m1 @ W2   (Bt = W2^T as [256][256] bf16)
// EPI 0: m2p[i][col] = silu(out + b2)               (CSR-ordered, bf16)
// EPI 1: trans[i] = cdp[i] * sum_col(silu(out+b2)*w3[col])
template <int EPI>
__global__ __launch_bounds__(512, 2) void k_edgeblk(
    const __bf16* __restrict__ PQ, const int* __restrict__ rowp, const int* __restrict__ colp,
    const float* __restrict__ radp, const float* __restrict__ d0p,
    const float* __restrict__ w1r, const float* __restrict__ w1d, const float* __restrict__ b1,
    const __bf16* __restrict__ Bt, const float* __restrict__ b2,
    __bf16* __restrict__ m2p,
    const float* __restrict__ w3, const float* __restrict__ cdp, float* __restrict__ transp) {
  constexpr int BM = 128, BK = 32;
  __shared__ __bf16 As[2][BM * BK];
  __shared__ __bf16 Bs[2][256 * BK];
  __shared__ float reds[BM][2];
  const int tid = threadIdx.x;
  const int lane = tid & 63;
  const int wave = tid >> 6;
  const int wm = wave >> 1, wn = wave & 1;   // 4x2 wave grid, wave tile 32x128
  const int m0 = blockIdx.x * BM;

  const int ar = tid >> 2, aq = tid & 3;     // A staging: row, 8-col quarter
  const int er = rowp[m0 + ar], ec = colp[m0 + ar];
  const float rad = radp[m0 + ar], dd0 = d0p[m0 + ar];
  const int aswz = (ar >> 1) & 3;
  const int br = tid >> 1, bg0 = (tid & 1) * 2;  // B staging: row, granule pair
  const int bswz = (br >> 1) & 3;

  f32x4 acc[2][8] = {};

  // ---- prologue: stage tile 0 ----
  {
    bf16x8 pv = *(const bf16x8*)(PQ + (size_t)er * 512 + aq * 8);
    bf16x8 qv = *(const bf16x8*)(PQ + (size_t)ec * 512 + 256 + aq * 8);
    float4 wra = *(const float4*)(w1r + aq * 8), wrb = *(const float4*)(w1r + aq * 8 + 4);
    float4 wda = *(const float4*)(w1d + aq * 8), wdb = *(const float4*)(w1d + aq * 8 + 4);
    float4 b1a = *(const float4*)(b1 + aq * 8), b1b = *(const float4*)(b1 + aq * 8 + 4);
    bf16x8 o;
    const float* wr4 = &wra.x; const float* wd4 = &wda.x; const float* bb4 = &b1a.x;
#pragma unroll
    for (int j = 0; j < 4; j++)
      o[j] = (__bf16)silu_f((float)pv[j] + (float)qv[j] + rad * wr4[j] + dd0 * wd4[j] + bb4[j]);
    const float* wr4b = &wrb.x; const float* wd4b = &wdb.x; const float* bb4b = &b1b.x;
#pragma unroll
    for (int j = 0; j < 4; j++)
      o[4 + j] = (__bf16)silu_f((float)pv[4 + j] + (float)qv[4 + j] + rad * wr4b[j] + dd0 * wd4b[j] + bb4b[j]);
    *(bf16x8*)&As[0][ar * BK + ((aq ^ aswz) << 3)] = o;
    bf16x8 v0 = *(const bf16x8*)(Bt + (size_t)br * 256 + bg0 * 8);
    bf16x8 v1 = *(const bf16x8*)(Bt + (size_t)br * 256 + bg0 * 8 + 8);
    *(bf16x8*)&Bs[0][br * BK + ((bg0 ^ bswz) << 3)] = v0;
    *(bf16x8*)&Bs[0][br * BK + (((bg0 + 1) ^ bswz) << 3)] = v1;
  }
  __syncthreads();

  int buf = 0;
  for (int t = 0; t < 8; ++t) {
    const int ktn = (t + 1) * BK;
    const bool has = (t < 7);
    bf16x8 pv, qv, v0, v1;
    float4 wra, wrb, wda, wdb, b1a, b1b;
    if (has) {   // issue next-tile loads early; latency hides under MFMA below
      pv = *(const bf16x8*)(PQ + (size_t)er * 512 + ktn + aq * 8);
      qv = *(const bf16x8*)(PQ + (size_t)ec * 512 + 256 + ktn + aq * 8);
      wra = *(const float4*)(w1r + ktn + aq * 8); wrb = *(const float4*)(w1r + ktn + aq * 8 + 4);
      wda = *(const float4*)(w1d + ktn + aq * 8); wdb = *(const float4*)(w1d + ktn + aq * 8 + 4);
      b1a = *(const float4*)(b1 + ktn + aq * 8);  b1b = *(const float4*)(b1 + ktn + aq * 8 + 4);
      v0 = *(const bf16x8*)(Bt + (size_t)br * 256 + ktn + bg0 * 8);
      v1 = *(const bf16x8*)(Bt + (size_t)br * 256 + ktn + bg0 * 8 + 8);
    }
    // compute current tile
    const int kg = lane >> 4;
    bf16x8 af[2];
#pragma unroll
    for (int fm = 0; fm < 2; fm++) {
      int r = wm * 32 + fm * 16 + (lane & 15);
      af[fm] = *(const bf16x8*)&As[buf][r * BK + ((kg ^ ((r >> 1) & 3)) << 3)];
    }
#pragma unroll
    for (int fn = 0; fn < 8; fn++) {
      int r = wn * 128 + fn * 16 + (lane & 15);
      bf16x8 bf = *(const bf16x8*)&Bs[buf][r * BK + ((kg ^ ((r >> 1) & 3)) << 3)];
#pragma unroll
      for (int fm = 0; fm < 2; fm++)
        acc[fm][fn] = __builtin_amdgcn_mfma_f32_16x16x32_bf16(af[fm], bf, acc[fm][fn], 0, 0, 0);
    }
    if (has) {  // finish staging: silu + LDS write into other buffer
      bf16x8 o;
      const float* wr4 = &wra.x; const float* wd4 = &wda.x; const float* bb4 = &b1a.x;
#pragma unroll
      for (int j = 0; j < 4; j++)
        o[j] = (__bf16)silu_f((float)pv[j] + (float)qv[j] + rad * wr4[j] + dd0 * wd4[j] + bb4[j]);
      const float* wr4b = &wrb.x; const float* wd4b = &wdb.x; const float* bb4b = &b1b.x;
#pragma unroll
      for (int j = 0; j < 4; j++)
        o[4 + j] = (__bf16)silu_f((float)pv[4 + j] + (float)qv[4 + j] + rad * wr4b[j] + dd0 * wd4b[j] + bb4b[j]);
      *(bf16x8*)&As[buf ^ 1][ar * BK + ((aq ^ aswz) << 3)] = o;
      *(bf16x8*)&Bs[buf ^ 1][br * BK + ((bg0 ^ bswz) << 3)] = v0;
      *(bf16x8*)&Bs[buf ^ 1][br * BK + (((bg0 + 1) ^ bswz) << 3)] = v1;
    }
    __syncthreads();
    buf ^= 1;
  }

  // ---- epilogue ----
  if (EPI == 0) {
#pragma unroll
    for (int fn = 0; fn < 8; fn++) {
      int col = wn * 128 + fn * 16 + (lane & 15);
      float bv = b2[col];
#pragma unroll
      for (int fm = 0; fm < 2; fm++) {
#pragma unroll
        for (int j = 0; j < 4; j++) {
          int row = m0 + wm * 32 + fm * 16 + ((lane >> 4) << 2) + j;
          m2p[(size_t)row * 256 + col] = (__bf16)silu_f(acc[fm][fn][j] + bv);
        }
      }
    }
  } else {
    float s[2][4] = {};
#pragma unroll
    for (int fn = 0; fn < 8; fn++) {
      int col = wn * 128 + fn * 16 + (lane & 15);
      float bv = b2[col], wv = w3[col];
#pragma unroll
      for (int fm = 0; fm < 2; fm++)
#pragma unroll
        for (int j = 0; j < 4; j++)
          s[fm][j] += silu_f(acc[fm][fn][j] + bv) * wv;
    }
#pragma unroll
    for (int off = 1; off < 16; off <<= 1)
#pragma unroll
      for (int fm = 0; fm < 2; fm++)
#pragma unroll
        for (int j = 0; j < 4; j++)
          s[fm][j] += __shfl_xor(s[fm][j], off, 64);
    if ((lane & 15) == 0) {
#pragma unroll
      for (int fm = 0; fm < 2; fm++)
#pragma unroll
        for (int j = 0; j < 4; j++)
          reds[wm * 32 + fm * 16 + ((lane >> 4) << 2) + j][wn] = s[fm][j];
    }
    __syncthreads();
    if (tid < BM) {
      float sv = reds[tid][0] + reds[tid][1];
      size_t i = (size_t)m0 + tid;
      transp[i * 3 + 0] = cdp[i * 3 + 0] * sv;
      transp[i * 3 + 1] = cdp[i * 3 + 1] * sv;
      transp[i * 3 + 2] = cdp[i * 3 + 2] * sv;
    }
  }
}

// ---------------- 64x64 MFMA GEMM, 2-phase double-buffered ----------------
// C = epi(A[M,K] @ Bt[N,K]^T + bias).  EPI: 1 silu->bf16, 2 residual f32+=v,bf16 out, 4 plain bf16
template <int EPI>
__global__ __launch_bounds__(256) void k_gemm64(const __bf16* __restrict__ A, const __bf16* __restrict__ Bt,
                                                const float* __restrict__ bias, __bf16* __restrict__ outb,
                                                float* __restrict__ outf, int M, int N, int K) {
  constexpr int BM = 64, BN = 64, BK = 64;
  __shared__ __bf16 As[2][BM * BK];
  __shared__ __bf16 Bs[2][BN * BK];
  const int tid = threadIdx.x;
  const int lane = tid & 63;
  const int wave = tid >> 6;
  const int wm = wave >> 1, wn = wave & 1;   // wave tile 32x32
  const size_t m0 = (size_t)blockIdx.x * BM;
  const size_t n0 = (size_t)blockIdx.y * BN;
  const int r0 = tid >> 3, g0 = tid & 7;     // staging: 2 granules per thread per matrix
  const int gs0 = (g0 ^ (r0 & 7)) << 3;

  f32x4 acc[2][2] = {};
  const int NT = K >> 6;

  {  // prologue: tile 0
    uint4 a0 = *(const uint4*)(A + (m0 + r0) * K + g0 * 8);
    uint4 a1 = *(const uint4*)(A + (m0 + r0 + 32) * K + g0 * 8);
    uint4 b0 = *(const uint4*)(Bt + (n0 + r0) * K + g0 * 8);
    uint4 b1 = *(const uint4*)(Bt + (n0 + r0 + 32) * K + g0 * 8);
    *(uint4*)&As[0][r0 * BK + gs0] = a0;
    *(uint4*)&As[0][(r0 + 32) * BK + gs0] = a1;
    *(uint4*)&Bs[0][r0 * BK + gs0] = b0;
    *(uint4*)&Bs[0][(r0 + 32) * BK + gs0] = b1;
  }
  __syncthreads();

  int buf = 0;
  for (int t = 0; t < NT; ++t) {
    const bool has = (t + 1 < NT);
    uint4 a0, a1, b0, b1;
    if (has) {
      int kt = (t + 1) << 6;
      a0 = *(const uint4*)(A + (m0 + r0) * K + kt + g0 * 8);
      a1 = *(const uint4*)(A + (m0 + r0 + 32) * K + kt + g0 * 8);
      b0 = *(const uint4*)(Bt + (n0 + r0) * K + kt + g0 * 8);
      b1 = *(const uint4*)(Bt + (n0 + r0 + 32) * K + kt + g0 * 8);
    }
#pragma unroll
    for (int ks = 0; ks < BK; ks += 32) {
      const int kg = (ks >> 3) + (lane >> 4);
      bf16x8 af[2], bfv[2];
#pragma unroll
      for (int fm = 0; fm < 2; fm++) {
        int r = wm * 32 + fm * 16 + (lane & 15);
        af[fm] = *(const bf16x8*)&As[buf][r * BK + ((kg ^ (r & 7)) << 3)];
      }
#pragma unroll
      for (int fn = 0; fn < 2; fn++) {
        int r = wn * 32 + fn * 16 + (lane & 15);
        bfv[fn] = *(const bf16x8*)&Bs[buf][r * BK + ((kg ^ (r & 7)) << 3)];
      }
#pragma unroll
      for (int fm = 0; fm < 2; fm++)
#pragma unroll
        for (int fn = 0; fn < 2; fn++)
          acc[fm][fn] = __builtin_amdgcn_mfma_f32_16x16x32_bf16(af[fm], bfv[fn], acc[fm][fn], 0, 0, 0);
    }
    if (has) {
      *(uint4*)&As[buf ^ 1][r0 * BK + gs0] = a0;
      *(uint4*)&As[buf ^ 1][(r0 + 32) * BK + gs0] = a1;
      *(uint4*)&Bs[buf ^ 1][r0 * BK + gs0] = b0;
      *(uint4*)&Bs[buf ^ 1][(r0 + 32) * BK + gs0] = b1;
    }
    __syncthreads();
    buf ^= 1;
  }

#pragma unroll
  for (int fm = 0; fm < 2; fm++) {
#pragma unroll
    for (int fn = 0; fn < 2; fn++) {
      const size_t col = n0 + wn * 32 + fn * 16 + (lane & 15);
      float bv = (EPI == 4) ? 0.f : bias[col];
#pragma unroll
      for (int j = 0; j < 4; j++) {
        size_t row = m0 + wm * 32 + fm * 16 + ((lane >> 4) << 2) + j;
        size_t idx = row * (size_t)N + col;
        float v = acc[fm][fn][j] + bv;
        if (EPI == 1) {
          outb[idx] = (__bf16)silu_f(v);
        } else if (EPI == 2) {
          float nh = outf[idx] + v;
          outf[idx] = nh;
          outb[idx] = (__bf16)nh;
        } else {
          outb[idx] = (__bf16)v;
        }
      }
    }
  }
}

// ---------------- host ----------------
extern "C" void kernel_launch(void* const* d_in, const int* in_sizes, int n_in,
                              void* d_out, int out_size, void* d_ws, size_t ws_size,
                              hipStream_t stream) {
  const float* h_in    = (const float*)d_in[0];
  const float* x_in    = (const float*)d_in[1];
  const int*   ei      = (const int*)d_in[2];
  const float* emb_w   = (const float*)d_in[3];
  const float* emb_b   = (const float*)d_in[4];
  const float* out_w   = (const float*)d_in[5];
  const float* out_b   = (const float*)d_in[6];
  const float* edge_w1 = (const float*)d_in[7];
  const float* edge_b1 = (const float*)d_in[8];
  const float* edge_w2 = (const float*)d_in[9];
  const float* edge_b2 = (const float*)d_in[10];
  const float* node_w1 = (const float*)d_in[11];
  const float* node_b1 = (const float*)d_in[12];
  const float* node_w2 = (const float*)d_in[13];
  const float* node_b2 = (const float*)d_in[14];
  const float* coord_w1 = (const float*)d_in[15];
  const float* coord_b1 = (const float*)d_in[16];
  const float* coord_w2 = (const float*)d_in[17];
  const float* coord_b2 = (const float*)d_in[18];
  const float* coord_w3 = (const float*)d_in[19];

  char* p = (char*)d_ws;
  auto alloc = [&](size_t bytes) -> void* {
    void* r = (void*)p;
    p += (bytes + 255) & ~(size_t)255;
    return r;
  };
  __bf16* e1T  = (__bf16*)alloc((size_t)6 * 512 * 256 * 2);
  __bf16* e2T  = (__bf16*)alloc((size_t)6 * 256 * 256 * 2);
  __bf16* n1T  = (__bf16*)alloc((size_t)6 * 256 * 512 * 2);
  __bf16* n2T  = (__bf16*)alloc((size_t)6 * 256 * 256 * 2);
  __bf16* c1T  = (__bf16*)alloc((size_t)3 * 512 * 256 * 2);
  __bf16* c2T  = (__bf16*)alloc((size_t)3 * 256 * 256 * 2);
  __bf16* h16  = (__bf16*)alloc((size_t)NN * HD * 2);
  __bf16* PQ16 = (__bf16*)alloc((size_t)NN * 512 * 2);
  __bf16* m2p  = (__bf16*)alloc((size_t)NE * HD * 2);
  __bf16* ncat = (__bf16*)alloc((size_t)NN * 512 * 2);
  __bf16* u    = (__bf16*)alloc((size_t)NN * HD * 2);
  float* hf    = (float*)alloc((size_t)NN * HD * 4);
  float* xc    = (float*)alloc((size_t)NN * 3 * 4);
  float* d0p   = (float*)alloc((size_t)NE * 4);
  float* radp  = (float*)alloc((size_t)NE * 4);
  float* cdp   = (float*)alloc((size_t)NE * 3 * 4);
  float* transp = (float*)alloc((size_t)NE * 3 * 4);
  int* cnt     = (int*)alloc((size_t)NN * 4);
  int* offs    = (int*)alloc((size_t)(NN + 1) * 4);
  int* cursor  = (int*)alloc((size_t)NN * 4);
  int* elist   = (int*)alloc((size_t)NE * 4);
  int* rowp    = (int*)alloc((size_t)NE * 4);
  int* colp    = (int*)alloc((size_t)NE * 4);

  TJobs jobs;
  int nj = 0;
  for (int gi = 0; gi < 6; gi++) {
    jobs.j[nj++] = { edge_w1 + (size_t)gi * 514 * 256,             e1T + (size_t)gi * 512 * 256,             256, 256 };
    jobs.j[nj++] = { edge_w1 + (size_t)gi * 514 * 256 + 256 * 256, e1T + (size_t)gi * 512 * 256 + 256 * 256, 256, 256 };
    jobs.j[nj++] = { edge_w2 + (size_t)gi * 256 * 256,             e2T + (size_t)gi * 256 * 256,             256, 256 };
    jobs.j[nj++] = { node_w1 + (size_t)gi * 512 * 256,             n1T + (size_t)gi * 256 * 512,             512, 256 };
    jobs.j[nj++] = { node_w2 + (size_t)gi * 256 * 256,             n2T + (size_t)gi * 256 * 256,             256, 256 };
  }
  for (int b = 0; b < 3; b++) {
    jobs.j[nj++] = { coord_w1 + (size_t)b * 514 * 256,             c1T + (size_t)b * 512 * 256,              256, 256 };
    jobs.j[nj++] = { coord_w1 + (size_t)b * 514 * 256 + 256 * 256, c1T + (size_t)b * 512 * 256 + 256 * 256,  256, 256 };
    jobs.j[nj++] = { coord_w2 + (size_t)b * 256 * 256,             c2T + (size_t)b * 256 * 256,              256, 256 };
  }

  hipMemsetAsync(cnt, 0, (size_t)NN * 4, stream);
  k_transpose<<<dim3(16, 8, 39), 256, 0, stream>>>(jobs);
  k_hist<<<NE / 256, 256, 0, stream>>>(ei, cnt);
  k_scan<<<1, 1024, 0, stream>>>(cnt, offs, cursor);
  k_scatter<<<NE / 256, 256, 0, stream>>>(ei, cursor, elist);
  k_csrinit<<<NE / 256, 256, 0, stream>>>(elist, ei, x_in, rowp, colp, d0p);
  k_copyx<<<(NN * 3 + 255) / 256, 256, 0, stream>>>(x_in, xc);
  k_embed<<<NN, 256, 0, stream>>>(h_in, emb_w, emb_b, hf, h16);

  int gi = 0;
  for (int b = 0; b < 3; b++) {
    k_geo<<<NE / 256, 256, 0, stream>>>(rowp, colp, xc, radp, cdp);
    for (int s = 0; s < 2; s++, gi++) {
      const float* w1 = edge_w1 + (size_t)gi * 514 * 256;
      // PQ = h @ [W1a|W1b]  -> bf16
      k_gemm64<4><<<dim3(64, 8), 256, 0, stream>>>(
          h16, e1T + (size_t)gi * 512 * 256, nullptr, PQ16, nullptr, NN, 512, 256);
      // fused edge layer1+layer2 -> m2p (CSR order)
      k_edgeblk<0><<<NE / 128, 512, 0, stream>>>(
          PQ16, rowp, colp, radp, d0p, w1 + 512 * 256, w1 + 513 * 256, edge_b1 + gi * 256,
          e2T + (size_t)gi * 256 * 256, edge_b2 + gi * 256, m2p, nullptr, nullptr, nullptr);
      k_segsum<<<NN, 256, 0, stream>>>(m2p, offs, h16, ncat);
      k_gemm64<1><<<dim3(64, 4), 256, 0, stream>>>(
          ncat, n1T + (size_t)gi * 256 * 512, node_b1 + gi * 256, u, nullptr, NN, 256, 512);
      k_gemm64<2><<<dim3(64, 4), 256, 0, stream>>>(
          u, n2T + (size_t)gi * 256 * 256, node_b2 + gi * 256, h16, hf, NN, 256, 256);
    }
    const float* w1c = coord_w1 + (size_t)b * 514 * 256;
    k_gemm64<4><<<dim3(64, 8), 256, 0, stream>>>(
        h16, c1T + (size_t)b * 512 * 256, nullptr, PQ16, nullptr, NN, 512, 256);
    k_edgeblk<1><<<NE / 128, 512, 0, stream>>>(
        PQ16, rowp, colp, radp, d0p, w1c + 512 * 256, w1c + 513 * 256, coord_b1 + b * 256,
        c2T + (size_t)b * 256 * 256, coord_b2 + b * 256, nullptr,
        coord_w3 + (size_t)b * 256, cdp, transp);
    k_xupd<<<NN / 256, 256, 0, stream>>>(transp, offs, xc);
  }
  k_outh<<<NN * 16 / 256, 256, 0, stream>>>(hf, out_w, out_b, (float*)d_out);
  k_outx<<<(NN * 3 + 255) / 256, 256, 0, stream>>>(xc, (float*)d_out + (size_t)NN * 16);
}

// Round 3
// 516.344 us; speedup vs baseline: 1.8217x; 1.1065x over previous
//
#include <hip/hip_runtime.h>
#include <hip/hip_bf16.h>
#include <cstdint>
#include <cstddef>

#define NN 4096
#define NE 65536
#define HD 256

typedef __attribute__((ext_vector_type(4))) float f32x4;
typedef __attribute__((ext_vector_type(8))) __bf16 bf16x8;

static __device__ __forceinline__ float silu_f(float v) {
  return v / (1.f + __expf(-v));
}

// ---------------- weight transpose/convert: f32 [K,N] -> bf16 [N,K] ----------
struct TJob { const float* src; __bf16* dst; int K; int N; };
struct TJobs { TJob j[39]; };

__global__ __launch_bounds__(256) void k_transpose(TJobs jobs) {
  TJob jb = jobs.j[blockIdx.z];
  int k0 = blockIdx.x << 5, n0 = blockIdx.y << 5;
  if (k0 >= jb.K || n0 >= jb.N) return;
  __shared__ float t[32][33];
  int tx = threadIdx.x & 31, ty = threadIdx.x >> 5;
#pragma unroll
  for (int r = ty; r < 32; r += 8)
    t[r][tx] = jb.src[(size_t)(k0 + r) * jb.N + n0 + tx];
  __syncthreads();
#pragma unroll
  for (int r = ty; r < 32; r += 8)
    jb.dst[(size_t)(n0 + r) * jb.K + k0 + tx] = (__bf16)t[tx][r];
}

// ---------------- CSR build ----------------
__global__ __launch_bounds__(256) void k_hist(const int* __restrict__ ei, int* __restrict__ cnt) {
  int e = blockIdx.x * 256 + threadIdx.x;
  atomicAdd(&cnt[ei[e]], 1);
}

__global__ __launch_bounds__(1024) void k_scan(const int* __restrict__ cnt, int* __restrict__ offs,
                                               int* __restrict__ cursor) {
  __shared__ int tmp[1024];
  int tid = threadIdx.x;
  int v[4]; int s = 0;
#pragma unroll
  for (int i = 0; i < 4; i++) { v[i] = cnt[tid * 4 + i]; s += v[i]; }
  tmp[tid] = s;
  __syncthreads();
  for (int o = 1; o < 1024; o <<= 1) {
    int t = (tid >= o) ? tmp[tid - o] : 0;
    __syncthreads();
    tmp[tid] += t;
    __syncthreads();
  }
  int base = (tid > 0) ? tmp[tid - 1] : 0;
#pragma unroll
  for (int i = 0; i < 4; i++) {
    offs[tid * 4 + i] = base; cursor[tid * 4 + i] = base; base += v[i];
  }
  if (tid == 1023) offs[4096] = base;
}

__global__ __launch_bounds__(256) void k_scatter(const int* __restrict__ ei, int* __restrict__ cursor,
                                                 int* __restrict__ elist) {
  int e = blockIdx.x * 256 + threadIdx.x;
  int pos = atomicAdd(&cursor[ei[e]], 1);
  elist[pos] = e;
}

// CSR metadata + dist0 (from initial x), all in CSR position order
__global__ __launch_bounds__(256) void k_csrinit(const int* __restrict__ elist, const int* __restrict__ ei,
                                                 const float* __restrict__ x, int* __restrict__ rowp,
                                                 int* __restrict__ colp, float* __restrict__ d0p) {
  int i = blockIdx.x * 256 + threadIdx.x;
  int e = elist[i];
  int r = ei[e], c = ei[NE + e];
  rowp[i] = r; colp[i] = c;
  float dx = x[r * 3 + 0] - x[c * 3 + 0];
  float dy = x[r * 3 + 1] - x[c * 3 + 1];
  float dz = x[r * 3 + 2] - x[c * 3 + 2];
  d0p[i] = dx * dx + dy * dy + dz * dz;
}

// per-block geometry (radial + coord_diff) in CSR order, from current coords
__global__ __launch_bounds__(256) void k_geo(const int* __restrict__ rowp, const int* __restrict__ colp,
                                             const float* __restrict__ x, float* __restrict__ radp,
                                             float* __restrict__ cdp) {
  int i = blockIdx.x * 256 + threadIdx.x;
  int r = rowp[i], c = colp[i];
  float dx = x[r * 3 + 0] - x[c * 3 + 0];
  float dy = x[r * 3 + 1] - x[c * 3 + 1];
  float dz = x[r * 3 + 2] - x[c * 3 + 2];
  float rad = dx * dx + dy * dy + dz * dz;
  radp[i] = rad;
  float inv = 1.f / (sqrtf(rad + 1e-8f) + 1.f);
  cdp[i * 3 + 0] = dx * inv; cdp[i * 3 + 1] = dy * inv; cdp[i * 3 + 2] = dz * inv;
}

// ---------------- misc small kernels ----------------
__global__ __launch_bounds__(256) void k_copyx(const float* __restrict__ x, float* __restrict__ xc) {
  int i = blockIdx.x * 256 + threadIdx.x;
  if (i < NN * 3) xc[i] = x[i];
}

__global__ __launch_bounds__(256) void k_embed(const float* __restrict__ h0, const float* __restrict__ W,
                                               const float* __restrict__ b, float* __restrict__ hf,
                                               __bf16* __restrict__ h16) {
  int n = blockIdx.x, c = threadIdx.x;
  float s = b[c];
#pragma unroll
  for (int i = 0; i < 16; i++) s += h0[n * 16 + i] * W[i * 256 + c];
  hf[(size_t)n * HD + c] = s;
  h16[(size_t)n * HD + c] = (__bf16)s;
}

// seg-sum over CSR (m2p is CSR-ordered -> streaming reads) + build ncat = [h16 | agg/100]
__global__ __launch_bounds__(256) void k_segsum(const __bf16* __restrict__ m2p, const int* __restrict__ offs,
                                                const __bf16* __restrict__ h16, __bf16* __restrict__ ncat) {
  __shared__ float sd[8][256];
  int n = blockIdx.x, t = threadIdx.x;
  int g = t >> 5, l = t & 31;
  int c0 = l << 3;
  float a[8] = {};
  int ib = offs[n], ie = offs[n + 1];
  for (int i = ib + g; i < ie; i += 8) {
    bf16x8 v = *(const bf16x8*)(m2p + (size_t)i * 256 + c0);
#pragma unroll
    for (int j = 0; j < 8; j++) a[j] += (float)v[j];
  }
#pragma unroll
  for (int j = 0; j < 8; j++) sd[g][c0 + j] = a[j];
  __syncthreads();
  float s = 0.f;
#pragma unroll
  for (int j = 0; j < 8; j++) s += sd[j][t];
  ncat[(size_t)n * 512 + t] = h16[(size_t)n * HD + t];
  ncat[(size_t)n * 512 + 256 + t] = (__bf16)(s * 0.01f);
}

__global__ __launch_bounds__(256) void k_xupd(const float* __restrict__ transp, const int* __restrict__ offs,
                                              float* __restrict__ xc) {
  int n = blockIdx.x * 256 + threadIdx.x;
  if (n >= NN) return;
  float a0 = 0.f, a1 = 0.f, a2 = 0.f;
  int i1 = offs[n + 1];
  for (int i = offs[n]; i < i1; i++) {
    a0 += transp[i * 3 + 0]; a1 += transp[i * 3 + 1]; a2 += transp[i * 3 + 2];
  }
  xc[n * 3 + 0] += a0 * 0.01f;
  xc[n * 3 + 1] += a1 * 0.01f;
  xc[n * 3 + 2] += a2 * 0.01f;
}

__global__ __launch_bounds__(256) void k_outh(const float* __restrict__ hf, const float* __restrict__ W,
                                              const float* __restrict__ b, float* __restrict__ out) {
  int t = blockIdx.x * 256 + threadIdx.x;
  int n = t >> 4, j = t & 15;
  float s = b[j];
  for (int c = 0; c < 256; c++) s += hf[(size_t)n * HD + c] * W[c * 16 + j];
  out[n * 16 + j] = s;
}

__global__ __launch_bounds__(256) void k_outx(const float* __restrict__ xc, float* __restrict__ out) {
  int i = blockIdx.x * 256 + threadIdx.x;
  if (i < NN * 3) out[i] = xc[i];
}

// ---------------- fused edge-block kernel (v2) ----------------
// Per block: 128 CSR-ordered edges x 256 outputs.
//   Phase 1 (burst): A[128][256] = silu(PQ[row] + PQ[col|256] + rad*w1r + d0*w1d + b1) -> LDS (XOR-swizzled)
//   Phase 2: 8 K-steps, B tile [256][32] streamed through single LDS buffer with depth-2 register prefetch.
//   Wave tile 64x64 (FM=4,FN=4), 8 waves (2 row-groups x 4 col-groups).
// EPI 0: m2p[i][col] = silu(out + b2)
// EPI 1: trans[i] = cdp[i] * sum_col(silu(out+b2)*w3[col])
template <int EPI>
__global__ __launch_bounds__(512, 4) void k_edgeblk(
    const __bf16* __restrict__ PQ, const int* __restrict__ rowp, const int* __restrict__ colp,
    const float* __restrict__ radp, const float* __restrict__ d0p,
    const float* __restrict__ w1r, const float* __restrict__ w1d, const float* __restrict__ b1,
    const __bf16* __restrict__ Bt, const float* __restrict__ b2,
    __bf16* __restrict__ m2p,
    const float* __restrict__ w3, const float* __restrict__ cdp, float* __restrict__ transp) {
  __shared__ alignas(16) char smem[81920];
  __bf16* As = (__bf16*)smem;              // [128][256] bf16, 64 KB, swizzled granules
  __bf16* Bs = (__bf16*)(smem + 65536);    // [256][32] bf16, 16 KB, swizzled granules
  float (*reds)[4] = (float(*)[4])smem;    // reused after MFMA loop (EPI1)

  const int tid = threadIdx.x;
  const int lane = tid & 63;
  const int wave = tid >> 6;
  const int wm = wave >> 2, wn = wave & 3;     // 2x4 wave grid, wave tile 64x64
  const int m0 = blockIdx.x * 128;

  // B prefetch mapping: thread -> row bn, granule pair
  const int bn = tid >> 1;
  const int bg = (tid & 1) * 2;
  const int bswz0 = (bg ^ ((bn >> 1) & 3)) << 3;       // elem offset of granule bg
  const int bswz1 = ((bg + 1) ^ ((bn >> 1) & 3)) << 3;

  // A-fill mapping
  const int ar = tid >> 2;       // edge row 0..127
  const int aq = tid & 3;        // granule phase
  const int er = rowp[m0 + ar], ec = colp[m0 + ar];
  const float rad = radp[m0 + ar], dd0 = d0p[m0 + ar];

  // ---- issue B tile 0 and 1 loads (depth-2) ----
  uint4 br0a = *(const uint4*)(Bt + (size_t)bn * 256 + bg * 8);
  uint4 br0b = *(const uint4*)(Bt + (size_t)bn * 256 + bg * 8 + 8);
  uint4 br1a = *(const uint4*)(Bt + (size_t)bn * 256 + 32 + bg * 8);
  uint4 br1b = *(const uint4*)(Bt + (size_t)bn * 256 + 32 + bg * 8 + 8);
  uint4 breg[2][2];
  breg[0][0] = br0a; breg[0][1] = br0b;
  breg[1][0] = br1a; breg[1][1] = br1b;

  // ---- Phase 1: A-fill burst (8 iterations x 8 channels) ----
#pragma unroll
  for (int i = 0; i < 8; i++) {
    int g = aq + 4 * i;            // granule 0..31, k = g*8
    int k = g * 8;
    bf16x8 pv = *(const bf16x8*)(PQ + (size_t)er * 512 + k);
    bf16x8 qv = *(const bf16x8*)(PQ + (size_t)ec * 512 + 256 + k);
    float4 wr0 = *(const float4*)(w1r + k),     wr1 = *(const float4*)(w1r + k + 4);
    float4 wd0 = *(const float4*)(w1d + k),     wd1 = *(const float4*)(w1d + k + 4);
    float4 bb0 = *(const float4*)(b1 + k),      bb1 = *(const float4*)(b1 + k + 4);
    bf16x8 o;
    const float* wrp0 = &wr0.x; const float* wdp0 = &wd0.x; const float* bbp0 = &bb0.x;
#pragma unroll
    for (int j = 0; j < 4; j++)
      o[j] = (__bf16)silu_f((float)pv[j] + (float)qv[j] + rad * wrp0[j] + dd0 * wdp0[j] + bbp0[j]);
    const float* wrp1 = &wr1.x; const float* wdp1 = &wd1.x; const float* bbp1 = &bb1.x;
#pragma unroll
    for (int j = 0; j < 4; j++)
      o[4 + j] = (__bf16)silu_f((float)pv[4 + j] + (float)qv[4 + j] + rad * wrp1[j] + dd0 * wdp1[j] + bbp1[j]);
    *(bf16x8*)&As[ar * 256 + ((g ^ (ar & 7)) << 3)] = o;
  }

  // write B tile 0
  *(uint4*)&Bs[bn * 32 + bswz0] = breg[0][0];
  *(uint4*)&Bs[bn * 32 + bswz1] = breg[0][1];
  __syncthreads();

  // ---- Phase 2: MFMA loop over 8 K-steps ----
  f32x4 acc[4][4] = {};
  const int kg = lane >> 4;            // k-granule within K-step
  const int l15 = lane & 15;

#pragma unroll
  for (int t = 0; t < 8; t++) {
    // issue load of tile t+2 into the reg slot freed by tile t
    if (t + 2 < 8) {
      breg[t & 1][0] = *(const uint4*)(Bt + (size_t)bn * 256 + (t + 2) * 32 + bg * 8);
      breg[t & 1][1] = *(const uint4*)(Bt + (size_t)bn * 256 + (t + 2) * 32 + bg * 8 + 8);
    }
    // MFMA on current Bs (tile t)
    bf16x8 bf[4];
#pragma unroll
    for (int fn = 0; fn < 4; fn++) {
      int n = wn * 64 + fn * 16 + l15;
      bf[fn] = *(const bf16x8*)&Bs[n * 32 + ((kg ^ ((n >> 1) & 3)) << 3)];
    }
#pragma unroll
    for (int fm = 0; fm < 4; fm++) {
      int r = wm * 64 + fm * 16 + l15;
      int G = t * 4 + kg;
      bf16x8 af = *(const bf16x8*)&As[r * 256 + ((G ^ (r & 7)) << 3)];
#pragma unroll
      for (int fn = 0; fn < 4; fn++)
        acc[fm][fn] = __builtin_amdgcn_mfma_f32_16x16x32_bf16(af, bf[fn], acc[fm][fn], 0, 0, 0);
    }
    __syncthreads();
    if (t < 7) {
      *(uint4*)&Bs[bn * 32 + bswz0] = breg[(t + 1) & 1][0];
      *(uint4*)&Bs[bn * 32 + bswz1] = breg[(t + 1) & 1][1];
      __syncthreads();
    }
  }

  // ---- epilogue ----
  if (EPI == 0) {
#pragma unroll
    for (int fm = 0; fm < 4; fm++) {
#pragma unroll
      for (int j = 0; j < 4; j++) {
        size_t row = m0 + wm * 64 + fm * 16 + ((lane >> 4) << 2) + j;
#pragma unroll
        for (int fn = 0; fn < 4; fn++) {
          int col = wn * 64 + fn * 16 + l15;
          m2p[row * 256 + col] = (__bf16)silu_f(acc[fm][fn][j] + b2[col]);
        }
      }
    }
  } else {
    float s[4][4];  // [fm][j]
#pragma unroll
    for (int fm = 0; fm < 4; fm++)
#pragma unroll
      for (int j = 0; j < 4; j++) s[fm][j] = 0.f;
#pragma unroll
    for (int fn = 0; fn < 4; fn++) {
      int col = wn * 64 + fn * 16 + l15;
      float bv = b2[col], wv = w3[col];
#pragma unroll
      for (int fm = 0; fm < 4; fm++)
#pragma unroll
        for (int j = 0; j < 4; j++)
          s[fm][j] += silu_f(acc[fm][fn][j] + bv) * wv;
    }
#pragma unroll
    for (int off = 1; off < 16; off <<= 1)
#pragma unroll
      for (int fm = 0; fm < 4; fm++)
#pragma unroll
        for (int j = 0; j < 4; j++)
          s[fm][j] += __shfl_xor(s[fm][j], off, 64);
    if (l15 == 0) {
#pragma unroll
      for (int fm = 0; fm < 4; fm++)
#pragma unroll
        for (int j = 0; j < 4; j++)
          reds[wm * 64 + fm * 16 + ((lane >> 4) << 2) + j][wn] = s[fm][j];
    }
    __syncthreads();
    if (tid < 128) {
      float sv = reds[tid][0] + reds[tid][1] + reds[tid][2] + reds[tid][3];
      size_t i = (size_t)m0 + tid;
      transp[i * 3 + 0] = cdp[i * 3 + 0] * sv;
      transp[i * 3 + 1] = cdp[i * 3 + 1] * sv;
      transp[i * 3 + 2] = cdp[i * 3 + 2] * sv;
    }
  }
}

// ---------------- 64x64 MFMA GEMM, 2-phase double-buffered ----------------
// C = epi(A[M,K] @ Bt[N,K]^T + bias).  EPI: 1 silu->bf16, 2 residual f32+=v,bf16 out, 4 plain bf16
template <int EPI>
__global__ __launch_bounds__(256) void k_gemm64(const __bf16* __restrict__ A, const __bf16* __restrict__ Bt,
                                                const float* __restrict__ bias, __bf16* __restrict__ outb,
                                                float* __restrict__ outf, int M, int N, int K) {
  constexpr int BM = 64, BN = 64, BK = 64;
  __shared__ __bf16 As[2][BM * BK];
  __shared__ __bf16 Bs[2][BN * BK];
  const int tid = threadIdx.x;
  const int lane = tid & 63;
  const int wave = tid >> 6;
  const int wm = wave >> 1, wn = wave & 1;   // wave tile 32x32
  const size_t m0 = (size_t)blockIdx.x * BM;
  const size_t n0 = (size_t)blockIdx.y * BN;
  const int r0 = tid >> 3, g0 = tid & 7;     // staging: 2 granules per thread per matrix
  const int gs0 = (g0 ^ (r0 & 7)) << 3;

  f32x4 acc[2][2] = {};
  const int NT = K >> 6;

  {  // prologue: tile 0
    uint4 a0 = *(const uint4*)(A + (m0 + r0) * K + g0 * 8);
    uint4 a1 = *(const uint4*)(A + (m0 + r0 + 32) * K + g0 * 8);
    uint4 b0 = *(const uint4*)(Bt + (n0 + r0) * K + g0 * 8);
    uint4 b1 = *(const uint4*)(Bt + (n0 + r0 + 32) * K + g0 * 8);
    *(uint4*)&As[0][r0 * BK + gs0] = a0;
    *(uint4*)&As[0][(r0 + 32) * BK + gs0] = a1;
    *(uint4*)&Bs[0][r0 * BK + gs0] = b0;
    *(uint4*)&Bs[0][(r0 + 32) * BK + gs0] = b1;
  }
  __syncthreads();

  int buf = 0;
  for (int t = 0; t < NT; ++t) {
    const bool has = (t + 1 < NT);
    uint4 a0, a1, b0, b1;
    if (has) {
      int kt = (t + 1) << 6;
      a0 = *(const uint4*)(A + (m0 + r0) * K + kt + g0 * 8);
      a1 = *(const uint4*)(A + (m0 + r0 + 32) * K + kt + g0 * 8);
      b0 = *(const uint4*)(Bt + (n0 + r0) * K + kt + g0 * 8);
      b1 = *(const uint4*)(Bt + (n0 + r0 + 32) * K + kt + g0 * 8);
    }
#pragma unroll
    for (int ks = 0; ks < BK; ks += 32) {
      const int kg = (ks >> 3) + (lane >> 4);
      bf16x8 af[2], bfv[2];
#pragma unroll
      for (int fm = 0; fm < 2; fm++) {
        int r = wm * 32 + fm * 16 + (lane & 15);
        af[fm] = *(const bf16x8*)&As[buf][r * BK + ((kg ^ (r & 7)) << 3)];
      }
#pragma unroll
      for (int fn = 0; fn < 2; fn++) {
        int r = wn * 32 + fn * 16 + (lane & 15);
        bfv[fn] = *(const bf16x8*)&Bs[buf][r * BK + ((kg ^ (r & 7)) << 3)];
      }
#pragma unroll
      for (int fm = 0; fm < 2; fm++)
#pragma unroll
        for (int fn = 0; fn < 2; fn++)
          acc[fm][fn] = __builtin_amdgcn_mfma_f32_16x16x32_bf16(af[fm], bfv[fn], acc[fm][fn], 0, 0, 0);
    }
    if (has) {
      *(uint4*)&As[buf ^ 1][r0 * BK + gs0] = a0;
      *(uint4*)&As[buf ^ 1][(r0 + 32) * BK + gs0] = a1;
      *(uint4*)&Bs[buf ^ 1][r0 * BK + gs0] = b0;
      *(uint4*)&Bs[buf ^ 1][(r0 + 32) * BK + gs0] = b1;
    }
    __syncthreads();
    buf ^= 1;
  }

#pragma unroll
  for (int fm = 0; fm < 2; fm++) {
#pragma unroll
    for (int fn = 0; fn < 2; fn++) {
      const size_t col = n0 + wn * 32 + fn * 16 + (lane & 15);
      float bv = (EPI == 4) ? 0.f : bias[col];
#pragma unroll
      for (int j = 0; j < 4; j++) {
        size_t row = m0 + wm * 32 + fm * 16 + ((lane >> 4) << 2) + j;
        size_t idx = row * (size_t)N + col;
        float v = acc[fm][fn][j] + bv;
        if (EPI == 1) {
          outb[idx] = (__bf16)silu_f(v);
        } else if (EPI == 2) {
          float nh = outf[idx] + v;
          outf[idx] = nh;
          outb[idx] = (__bf16)nh;
        } else {
          outb[idx] = (__bf16)v;
        }
      }
    }
  }
}

// ---------------- host ----------------
extern "C" void kernel_launch(void* const* d_in, const int* in_sizes, int n_in,
                              void* d_out, int out_size, void* d_ws, size_t ws_size,
                              hipStream_t stream) {
  const float* h_in    = (const float*)d_in[0];
  const float* x_in    = (const float*)d_in[1];
  const int*   ei      = (const int*)d_in[2];
  const float* emb_w   = (const float*)d_in[3];
  const float* emb_b   = (const float*)d_in[4];
  const float* out_w   = (const float*)d_in[5];
  const float* out_b   = (const float*)d_in[6];
  const float* edge_w1 = (const float*)d_in[7];
  const float* edge_b1 = (const float*)d_in[8];
  const float* edge_w2 = (const float*)d_in[9];
  const float* edge_b2 = (const float*)d_in[10];
  const float* node_w1 = (const float*)d_in[11];
  const float* node_b1 = (const float*)d_in[12];
  const float* node_w2 = (const float*)d_in[13];
  const float* node_b2 = (const float*)d_in[14];
  const float* coord_w1 = (const float*)d_in[15];
  const float* coord_b1 = (const float*)d_in[16];
  const float* coord_w2 = (const float*)d_in[17];
  const float* coord_b2 = (const float*)d_in[18];
  const float* coord_w3 = (const float*)d_in[19];

  char* p = (char*)d_ws;
  auto alloc = [&](size_t bytes) -> void* {
    void* r = (void*)p;
    p += (bytes + 255) & ~(size_t)255;
    return r;
  };
  __bf16* e1T  = (__bf16*)alloc((size_t)6 * 512 * 256 * 2);
  __bf16* e2T  = (__bf16*)alloc((size_t)6 * 256 * 256 * 2);
  __bf16* n1T  = (__bf16*)alloc((size_t)6 * 256 * 512 * 2);
  __bf16* n2T  = (__bf16*)alloc((size_t)6 * 256 * 256 * 2);
  __bf16* c1T  = (__bf16*)alloc((size_t)3 * 512 * 256 * 2);
  __bf16* c2T  = (__bf16*)alloc((size_t)3 * 256 * 256 * 2);
  __bf16* h16  = (__bf16*)alloc((size_t)NN * HD * 2);
  __bf16* PQ16 = (__bf16*)alloc((size_t)NN * 512 * 2);
  __bf16* m2p  = (__bf16*)alloc((size_t)NE * HD * 2);
  __bf16* ncat = (__bf16*)alloc((size_t)NN * 512 * 2);
  __bf16* u    = (__bf16*)alloc((size_t)NN * HD * 2);
  float* hf    = (float*)alloc((size_t)NN * HD * 4);
  float* xc    = (float*)alloc((size_t)NN * 3 * 4);
  float* d0p   = (float*)alloc((size_t)NE * 4);
  float* radp  = (float*)alloc((size_t)NE * 4);
  float* cdp   = (float*)alloc((size_t)NE * 3 * 4);
  float* transp = (float*)alloc((size_t)NE * 3 * 4);
  int* cnt     = (int*)alloc((size_t)NN * 4);
  int* offs    = (int*)alloc((size_t)(NN + 1) * 4);
  int* cursor  = (int*)alloc((size_t)NN * 4);
  int* elist   = (int*)alloc((size_t)NE * 4);
  int* rowp    = (int*)alloc((size_t)NE * 4);
  int* colp    = (int*)alloc((size_t)NE * 4);

  TJobs jobs;
  int nj = 0;
  for (int gi = 0; gi < 6; gi++) {
    jobs.j[nj++] = { edge_w1 + (size_t)gi * 514 * 256,             e1T + (size_t)gi * 512 * 256,             256, 256 };
    jobs.j[nj++] = { edge_w1 + (size_t)gi * 514 * 256 + 256 * 256, e1T + (size_t)gi * 512 * 256 + 256 * 256, 256, 256 };
    jobs.j[nj++] = { edge_w2 + (size_t)gi * 256 * 256,             e2T + (size_t)gi * 256 * 256,             256, 256 };
    jobs.j[nj++] = { node_w1 + (size_t)gi * 512 * 256,             n1T + (size_t)gi * 256 * 512,             512, 256 };
    jobs.j[nj++] = { node_w2 + (size_t)gi * 256 * 256,             n2T + (size_t)gi * 256 * 256,             256, 256 };
  }
  for (int b = 0; b < 3; b++) {
    jobs.j[nj++] = { coord_w1 + (size_t)b * 514 * 256,             c1T + (size_t)b * 512 * 256,              256, 256 };
    jobs.j[nj++] = { coord_w1 + (size_t)b * 514 * 256 + 256 * 256, c1T + (size_t)b * 512 * 256 + 256 * 256,  256, 256 };
    jobs.j[nj++] = { coord_w2 + (size_t)b * 256 * 256,             c2T + (size_t)b * 256 * 256,              256, 256 };
  }

  hipMemsetAsync(cnt, 0, (size_t)NN * 4, stream);
  k_transpose<<<dim3(16, 8, 39), 256, 0, stream>>>(jobs);
  k_hist<<<NE / 256, 256, 0, stream>>>(ei, cnt);
  k_scan<<<1, 1024, 0, stream>>>(cnt, offs, cursor);
  k_scatter<<<NE / 256, 256, 0, stream>>>(ei, cursor, elist);
  k_csrinit<<<NE / 256, 256, 0, stream>>>(elist, ei, x_in, rowp, colp, d0p);
  k_copyx<<<(NN * 3 + 255) / 256, 256, 0, stream>>>(x_in, xc);
  k_embed<<<NN, 256, 0, stream>>>(h_in, emb_w, emb_b, hf, h16);

  int gi = 0;
  for (int b = 0; b < 3; b++) {
    k_geo<<<NE / 256, 256, 0, stream>>>(rowp, colp, xc, radp, cdp);
    for (int s = 0; s < 2; s++, gi++) {
      const float* w1 = edge_w1 + (size_t)gi * 514 * 256;
      // PQ = h @ [W1a|W1b]  -> bf16
      k_gemm64<4><<<dim3(64, 8), 256, 0, stream>>>(
          h16, e1T + (size_t)gi * 512 * 256, nullptr, PQ16, nullptr, NN, 512, 256);
      // fused edge layer1+layer2 -> m2p (CSR order)
      k_edgeblk<0><<<NE / 128, 512, 0, stream>>>(
          PQ16, rowp, colp, radp, d0p, w1 + 512 * 256, w1 + 513 * 256, edge_b1 + gi * 256,
          e2T + (size_t)gi * 256 * 256, edge_b2 + gi * 256, m2p, nullptr, nullptr, nullptr);
      k_segsum<<<NN, 256, 0, stream>>>(m2p, offs, h16, ncat);
      k_gemm64<1><<<dim3(64, 4), 256, 0, stream>>>(
          ncat, n1T + (size_t)gi * 256 * 512, node_b1 + gi * 256, u, nullptr, NN, 256, 512);
      k_gemm64<2><<<dim3(64, 4), 256, 0, stream>>>(
          u, n2T + (size_t)gi * 256 * 256, node_b2 + gi * 256, h16, hf, NN, 256, 256);
    }
    const float* w1c = coord_w1 + (size_t)b * 514 * 256;
    k_gemm64<4><<<dim3(64, 8), 256, 0, stream>>>(
        h16, c1T + (size_t)b * 512 * 256, nullptr, PQ16, nullptr, NN, 512, 256);
    k_edgeblk<1><<<NE / 128, 512, 0, stream>>>(
        PQ16, rowp, colp, radp, d0p, w1c + 512 * 256, w1c + 513 * 256, coord_b1 + b * 256,
        c2T + (size_t)b * 256 * 256, coord_b2 + b * 256, nullptr,
        coord_w3 + (size_t)b * 256, cdp, transp);
    k_xupd<<<NN / 256, 256, 0, stream>>>(transp, offs, xc);
  }
  k_outh<<<NN * 16 / 256, 256, 0, stream>>>(hf, out_w, out_b, (float*)d_out);
  k_outx<<<(NN * 3 + 255) / 256, 256, 0, stream>>>(xc, (float*)d_out + (size_t)NN * 16);
}